// Round 3
// baseline (622.302 us; speedup 1.0000x reference)
//
#include <hip/hip_runtime.h>

typedef unsigned short u16;
typedef __attribute__((ext_vector_type(8))) short short8;
typedef __attribute__((ext_vector_type(4))) float floatx4;

#define B_  16
#define S_  384
#define D_  768
#define H_  12
#define DH_ 64
#define FF_ 3072

__device__ __forceinline__ float b2f(u16 h) { return __uint_as_float(((unsigned)h) << 16); }
__device__ __forceinline__ u16 f2b(float f) {
  unsigned u = __float_as_uint(f);
  u += 0x7fffu + ((u >> 16) & 1u);
  return (u16)(u >> 16);
}

// diagnostic sentinel: ws too small
__global__ __launch_bounds__(256) void fill_sentinel(u16* out, int n) {
  int i = blockIdx.x * 256 + threadIdx.x;
  if (i < n) out[i] = 0x42DE;  // bf16 111.0
}

// ---------------- dtype detect: bf16 data has no exponent field >= 0xC0 ----------------
__global__ __launch_bounds__(256) void detect_dtype(const u16* __restrict__ x, int* flag) {
  __shared__ int cnt;
  if (threadIdx.x == 0) cnt = 0;
  __syncthreads();
  int c = 0;
  for (int i = threadIdx.x; i < 8192; i += 256) {
    const unsigned e = (x[i] >> 7) & 0xFFu;
    if (e >= 0xC0u) ++c;  // |v| >= 2^65: impossible for bf16 N(0,1); ~25% for fp32 low-halves
  }
  atomicAdd(&cnt, c);
  __syncthreads();
  if (threadIdx.x == 0) *flag = (cnt > 64) ? 1 : 0;  // 1 = inputs are fp32
}

// ---------------- input conversion (dual dtype -> bf16) ----------------
__global__ __launch_bounds__(256) void convert_in(const void* __restrict__ src,
                                                  u16* __restrict__ dst, int n,
                                                  const int* __restrict__ flag) {
  const int i = blockIdx.x * 256 + threadIdx.x;
  if (i >= n) return;
  if (*flag) dst[i] = f2b(((const float*)src)[i]);
  else dst[i] = ((const u16*)src)[i];
}

// ---------------- weight transpose + convert: out[c][r] = in[r][c] ----------------
__global__ __launch_bounds__(256) void transpose_cv(const void* __restrict__ in,
                                                    u16* __restrict__ out, int R, int C,
                                                    const int* __restrict__ flag) {
  __shared__ u16 t[32][33];
  const int f32 = *flag;
  const int bc = blockIdx.x * 32, br = blockIdx.y * 32;
  const int tx = threadIdx.x & 31, ty = threadIdx.x >> 5;  // ty 0..7
  for (int i = ty; i < 32; i += 8) {
    const size_t idx = (size_t)(br + i) * C + bc + tx;
    t[i][tx] = f32 ? f2b(((const float*)in)[idx]) : ((const u16*)in)[idx];
  }
  __syncthreads();
  for (int i = ty; i < 32; i += 8) out[(size_t)(bc + i) * R + br + tx] = t[tx][i];
}

// ---------------- generic GEMM: C[M,N] = A[M,K] @ Bt[N,K]^T ----------------
enum { F_BIAS = 1, F_RELU = 2, F_RES = 4, F_DUAL = 8, F_VT = 16 };

template <int FLAGS>
__global__ __launch_bounds__(256) void gemm_bt(
    const u16* __restrict__ A, const u16* __restrict__ Bt,
    u16* __restrict__ out0, u16* __restrict__ out1,
    const u16* __restrict__ bias0, const u16* __restrict__ bias1,
    const u16* __restrict__ res, int M, int N, int K) {
  __shared__ u16 As[128][40];   // +8 pad keeps 16B alignment, breaks pow2 stride
  __shared__ u16 Bs[128][40];
  const int m0 = blockIdx.y * 128;
  const int n0 = blockIdx.x * 128;
  const int tid = threadIdx.x;
  const int wid = tid >> 6, lane = tid & 63;
  const int wm = (wid & 1) * 64, wn = (wid >> 1) * 64;
  const int lm = lane & 15, quad = lane >> 4;

  floatx4 acc[4][4];
#pragma unroll
  for (int i = 0; i < 4; ++i)
#pragma unroll
    for (int j = 0; j < 4; ++j) acc[i][j] = (floatx4){0.f, 0.f, 0.f, 0.f};

  const int r0 = tid >> 2;          // 0..63
  const int c0 = (tid & 3) * 8;     // 0,8,16,24
  for (int k0 = 0; k0 < K; k0 += 32) {
#pragma unroll
    for (int it = 0; it < 2; ++it) {
      const int row = r0 + it * 64;
      const int ga = m0 + row;
      short8 av;
      if (ga < M) av = *(const short8*)(A + (size_t)ga * K + k0 + c0);
      else av = (short8){0, 0, 0, 0, 0, 0, 0, 0};
      *(short8*)(&As[row][c0]) = av;
      const int gb = n0 + row;  // N is always a multiple of 128
      *(short8*)(&Bs[row][c0]) = *(const short8*)(Bt + (size_t)gb * K + k0 + c0);
    }
    __syncthreads();
    short8 af[4], bfr[4];
#pragma unroll
    for (int t = 0; t < 4; ++t) {
      af[t] = *(const short8*)(&As[wm + t * 16 + lm][quad * 8]);
      bfr[t] = *(const short8*)(&Bs[wn + t * 16 + lm][quad * 8]);
    }
#pragma unroll
    for (int tm = 0; tm < 4; ++tm)
#pragma unroll
      for (int tn = 0; tn < 4; ++tn)
        acc[tm][tn] = __builtin_amdgcn_mfma_f32_16x16x32_bf16(af[tm], bfr[tn], acc[tm][tn], 0, 0, 0);
    __syncthreads();
  }
#pragma unroll
  for (int tm = 0; tm < 4; ++tm) {
#pragma unroll
    for (int tn = 0; tn < 4; ++tn) {
      const int gcol = n0 + wn + tn * 16 + lm;
#pragma unroll
      for (int r = 0; r < 4; ++r) {
        const int grow = m0 + wm + tm * 16 + quad * 4 + r;
        if (grow >= M) continue;
        float val = acc[tm][tn][r];
        if (FLAGS & F_BIAS) val += b2f(bias0[gcol]);
        if (FLAGS & F_RES) val += b2f(res[(size_t)grow * N + gcol]);
        if (FLAGS & F_RELU) val = fmaxf(val, 0.f);
        if (FLAGS & F_DUAL) {
          out0[(size_t)grow * N + gcol] = f2b(val + b2f(bias0[gcol]));
          out1[(size_t)grow * N + gcol] = f2b(val + b2f(bias1[gcol]));
        } else if (FLAGS & F_VT) {
          const int bb = grow / S_, s = grow % S_;
          out0[((size_t)bb * D_ + gcol) * S_ + s] = f2b(val);
        } else {
          out0[(size_t)grow * N + gcol] = f2b(val);
        }
      }
    }
  }
}

// ---------------- fused rel-pos attention ----------------
__global__ __launch_bounds__(256) void attn_kernel(
    const u16* __restrict__ qu, const u16* __restrict__ qv,
    const u16* __restrict__ kb, const u16* __restrict__ vt,
    const u16* __restrict__ rb, u16* __restrict__ attn) {
  __shared__ float sc[16][384];      // scores; reused for PV partials
  __shared__ u16 p[16][392];         // unnormalized softmax (bf16)
  __shared__ float red[16][16];
  __shared__ float rmax[16], rsum[16];

  const int qt = blockIdx.x, bh = blockIdx.y;
  const int b = bh / H_, h = bh % H_;
  const int i0 = qt * 16;
  const int tid = threadIdx.x, wid = tid >> 6, lane = tid & 63;
  const int lm = lane & 15, quad = lane >> 4;
  float* scf = &sc[0][0];

  for (int i = tid; i < 16 * 384; i += 256) scf[i] = 0.f;
  __syncthreads();

  const size_t qrow = ((size_t)(b * S_ + i0 + lm)) * D_ + h * DH_;
  // ---- B_D: E = (q+v) @ r^T over rel offsets, scatter at j = row - trel + 383 ----
  {
    const short8 a0 = *(const short8*)(qv + qrow + quad * 8);
    const short8 a1 = *(const short8*)(qv + qrow + 32 + quad * 8);
    for (int tt = wid; tt < 25; tt += 4) {
      const int trel = tt * 16 + lm;
      int t = i0 + trel;
      if (t > 766) t = 766;  // pad tile; those cols map to j<0 and are discarded
      const size_t rrow = (size_t)t * D_ + h * DH_;
      const short8 b0 = *(const short8*)(rb + rrow + quad * 8);
      const short8 b1 = *(const short8*)(rb + rrow + 32 + quad * 8);
      floatx4 e = (floatx4){0.f, 0.f, 0.f, 0.f};
      e = __builtin_amdgcn_mfma_f32_16x16x32_bf16(a0, b0, e, 0, 0, 0);
      e = __builtin_amdgcn_mfma_f32_16x16x32_bf16(a1, b1, e, 0, 0, 0);
#pragma unroll
      for (int r = 0; r < 4; ++r) {
        const int row = quad * 4 + r;
        const int j = row - trel + 383;
        if (j >= 0 && j < 384) sc[row][j] += e[r];  // disjoint (row,j) across waves/tiles
      }
    }
  }
  __syncthreads();
  // ---- A_C: (q+u) @ k^T, wave w owns keys [w*96, w*96+96) ----
  {
    const short8 a0 = *(const short8*)(qu + qrow + quad * 8);
    const short8 a1 = *(const short8*)(qu + qrow + 32 + quad * 8);
    for (int q = 0; q < 6; ++q) {
      const int j0 = (wid * 6 + q) * 16;
      const size_t krow = ((size_t)(b * S_ + j0 + lm)) * D_ + h * DH_;
      const short8 b0 = *(const short8*)(kb + krow + quad * 8);
      const short8 b1 = *(const short8*)(kb + krow + 32 + quad * 8);
      floatx4 e = (floatx4){0.f, 0.f, 0.f, 0.f};
      e = __builtin_amdgcn_mfma_f32_16x16x32_bf16(a0, b0, e, 0, 0, 0);
      e = __builtin_amdgcn_mfma_f32_16x16x32_bf16(a1, b1, e, 0, 0, 0);
#pragma unroll
      for (int r = 0; r < 4; ++r) {
        const int row = quad * 4 + r;
        sc[row][j0 + lm] = (sc[row][j0 + lm] + e[r]) * 0.125f;  // 1/sqrt(64)
      }
    }
  }
  __syncthreads();
  // ---- softmax (unnormalized P; divide at the end) ----
  {
    const int row = tid >> 4, sub = tid & 15;
    float lmax = -1e30f;
    for (int cc = 0; cc < 24; ++cc) lmax = fmaxf(lmax, sc[row][sub + cc * 16]);
    red[row][sub] = lmax;
    __syncthreads();
    if (sub == 0) {
      float m = red[row][0];
      for (int i = 1; i < 16; ++i) m = fmaxf(m, red[row][i]);
      rmax[row] = m;
    }
    __syncthreads();
    const float m = rmax[row];
    float lsum = 0.f;
    for (int cc = 0; cc < 24; ++cc) {
      const int c = sub + cc * 16;
      const float e = __expf(sc[row][c] - m);
      p[row][c] = f2b(e);
      lsum += e;
    }
    red[row][sub] = lsum;
    __syncthreads();
    if (sub == 0) {
      float s2 = 0.f;
      for (int i = 0; i < 16; ++i) s2 += red[row][i];
      rsum[row] = s2;
    }
    __syncthreads();
  }
  // ---- PV: wave w owns keys [w*96, w*96+96) ----
  floatx4 o[4];
#pragma unroll
  for (int nt = 0; nt < 4; ++nt) o[nt] = (floatx4){0.f, 0.f, 0.f, 0.f};
  for (int kk = 0; kk < 3; ++kk) {
    const int kbase = wid * 96 + kk * 32;
    const short8 af = *(const short8*)(&p[lm][kbase + quad * 8]);
#pragma unroll
    for (int nt = 0; nt < 4; ++nt) {
      const size_t vrow = ((size_t)(b * D_ + h * DH_ + nt * 16 + lm)) * S_;
      const short8 bv = *(const short8*)(vt + vrow + kbase + quad * 8);
      o[nt] = __builtin_amdgcn_mfma_f32_16x16x32_bf16(af, bv, o[nt], 0, 0, 0);
    }
  }
  __syncthreads();
#pragma unroll
  for (int nt = 0; nt < 4; ++nt)
#pragma unroll
    for (int r = 0; r < 4; ++r) {
      const int row = quad * 4 + r, dh = nt * 16 + lm;
      scf[wid * 1024 + row * 64 + dh] = o[nt][r];
    }
  __syncthreads();
  for (int t = tid; t < 1024; t += 256) {
    const int row = t >> 6, dh = t & 63;
    float v = scf[row * 64 + dh] + scf[1024 + row * 64 + dh] +
              scf[2048 + row * 64 + dh] + scf[3072 + row * 64 + dh];
    v /= rsum[row];
    attn[((size_t)(b * S_ + i0 + row)) * D_ + h * DH_ + dh] = f2b(v);
  }
}

// ---------------- row layernorm: 1 wave per row; dual-dtype store for final ----------------
__global__ __launch_bounds__(256) void ln_kernel(const u16* __restrict__ y,
                                                 const u16* __restrict__ g,
                                                 const u16* __restrict__ bb,
                                                 void* __restrict__ outv,
                                                 const int* __restrict__ flag, int dual) {
  const int row = blockIdx.x * 4 + (threadIdx.x >> 6);
  const int lane = threadIdx.x & 63;
  const u16* yr = y + (size_t)row * D_;
  float vbuf[12], s = 0.f, s2 = 0.f;
#pragma unroll
  for (int i = 0; i < 12; ++i) {
    const float x = b2f(yr[lane + i * 64]);
    vbuf[i] = x;
    s += x;
    s2 += x * x;
  }
#pragma unroll
  for (int off = 32; off; off >>= 1) {
    s += __shfl_down(s, off);
    s2 += __shfl_down(s2, off);
  }
  s = __shfl(s, 0);
  s2 = __shfl(s2, 0);
  const float mean = s * (1.f / 768.f);
  const float var = s2 * (1.f / 768.f) - mean * mean;
  const float inv = rsqrtf(var + 1e-5f);
  const int f32out = dual && *flag;
#pragma unroll
  for (int i = 0; i < 12; ++i) {
    const int c = lane + i * 64;
    const float val = (vbuf[i] - mean) * inv * b2f(g[c]) + b2f(bb[c]);
    if (f32out) ((float*)outv)[(size_t)row * D_ + c] = val;
    else ((u16*)outv)[(size_t)row * D_ + c] = f2b(val);
  }
}

// ---------------- host ----------------
extern "C" void kernel_launch(void* const* d_in, const int* in_sizes, int n_in,
                              void* d_out, int out_size, void* d_ws, size_t ws_size,
                              hipStream_t stream) {
  const void* x    = d_in[0];
  const void* pe   = d_in[1];
  const void* Wq   = d_in[2];
  const void* Wk   = d_in[3];
  const void* Wv   = d_in[4];
  const void* Wr   = d_in[5];
  const void* ub   = d_in[6];
  const void* vb   = d_in[7];
  const void* Wo   = d_in[8];
  const void* ln1g = d_in[9];
  const void* ln1b = d_in[10];
  const void* ln2g = d_in[11];
  const void* ln2b = d_in[12];
  const void* W1   = d_in[13];
  const void* b1   = d_in[14];
  const void* W2   = d_in[15];
  const void* b2   = d_in[16];
  char* ws = (char*)d_ws;

  constexpr int N_X  = B_ * S_ * D_;          // 4,718,592
  constexpr int N_PE = (2 * S_ - 1) * D_;     // 589,056

  // ws layout (bytes); lifetimes allow heavy aliasing. high-water 63,733,760
  constexpr size_t O_W   = 0;                 // 7 transposed weights, 15,335,424
  constexpr size_t O_SM  = 15335424;          // flag + small converted tensors (32 KB)
  constexpr size_t O_XB  = 15368192;          // xb | y1 (in-place) | ff[0]
  constexpr size_t O_QU  = 24805376;          // qu | ff[1]
  constexpr size_t O_QV  = 34242560;          // peb, then qv | ff[2]
  constexpr size_t O_KB  = 43679744;          // kb | ff[3]
  constexpr size_t O_VT  = 53116928;          // vt | x1 | y2 (in-place)
  constexpr size_t O_RB  = 62554112;          // rb
  constexpr size_t NEEDED = 63733760;

  if (ws_size < NEEDED) {
    fill_sentinel<<<(out_size + 255) / 256, 256, 0, stream>>>((u16*)d_out, out_size);
    return;
  }

  int* flag = (int*)(ws + O_SM);
  u16* ubc  = (u16*)(ws + O_SM + 128);
  u16* vbc  = (u16*)(ws + O_SM + 1664);
  u16* b1c  = (u16*)(ws + O_SM + 3200);
  u16* b2c  = (u16*)(ws + O_SM + 9344);
  u16* g1c  = (u16*)(ws + O_SM + 10880);
  u16* be1c = (u16*)(ws + O_SM + 12416);
  u16* g2c  = (u16*)(ws + O_SM + 13952);
  u16* be2c = (u16*)(ws + O_SM + 15488);

  u16* wtq = (u16*)(ws + O_W);
  u16* wtk = wtq + (size_t)D_ * D_;
  u16* wtv = wtk + (size_t)D_ * D_;
  u16* wtr = wtv + (size_t)D_ * D_;
  u16* wto = wtr + (size_t)D_ * D_;
  u16* wt1 = wto + (size_t)D_ * D_;
  u16* wt2 = wt1 + (size_t)D_ * FF_;

  u16* xb  = (u16*)(ws + O_XB);
  u16* quB = (u16*)(ws + O_QU);
  u16* peb = (u16*)(ws + O_QV);   // dies before qv is written
  u16* qvB = (u16*)(ws + O_QV);
  u16* kbB = (u16*)(ws + O_KB);
  u16* vtB = (u16*)(ws + O_VT);
  u16* rbB = (u16*)(ws + O_RB);
  u16* atB = (u16*)d_out;         // bf16 scratch in d_out; dead after Wo-GEMM
  u16* y1B = xb;                  // in-place residual (element-wise bijective)
  u16* x1B = (u16*)(ws + O_VT);   // vt dead after attention
  u16* ffB = xb;                  // 37.75 MB contiguous: xb+qu+qv+kb slots
  u16* y2B = x1B;                 // in-place residual

  // --- detect + convert ---
  detect_dtype<<<1, 256, 0, stream>>>((const u16*)x, flag);
  convert_in<<<(N_X + 255) / 256, 256, 0, stream>>>(x, xb, N_X, flag);
  convert_in<<<(N_PE + 255) / 256, 256, 0, stream>>>(pe, peb, N_PE, flag);
  convert_in<<<3, 256, 0, stream>>>(ub, ubc, 768, flag);
  convert_in<<<3, 256, 0, stream>>>(vb, vbc, 768, flag);
  convert_in<<<12, 256, 0, stream>>>(b1, b1c, 3072, flag);
  convert_in<<<3, 256, 0, stream>>>(b2, b2c, 768, flag);
  convert_in<<<3, 256, 0, stream>>>(ln1g, g1c, 768, flag);
  convert_in<<<3, 256, 0, stream>>>(ln1b, be1c, 768, flag);
  convert_in<<<3, 256, 0, stream>>>(ln2g, g2c, 768, flag);
  convert_in<<<3, 256, 0, stream>>>(ln2b, be2c, 768, flag);
  transpose_cv<<<dim3(24, 24), 256, 0, stream>>>(Wq, wtq, D_, D_, flag);
  transpose_cv<<<dim3(24, 24), 256, 0, stream>>>(Wk, wtk, D_, D_, flag);
  transpose_cv<<<dim3(24, 24), 256, 0, stream>>>(Wv, wtv, D_, D_, flag);
  transpose_cv<<<dim3(24, 24), 256, 0, stream>>>(Wr, wtr, D_, D_, flag);
  transpose_cv<<<dim3(24, 24), 256, 0, stream>>>(Wo, wto, D_, D_, flag);
  transpose_cv<<<dim3(96, 24), 256, 0, stream>>>(W1, wt1, D_, FF_, flag);
  transpose_cv<<<dim3(24, 96), 256, 0, stream>>>(W2, wt2, FF_, D_, flag);

  // --- projections (rb first: peb aliases qv) ---
  gemm_bt<0><<<dim3(6, 6), 256, 0, stream>>>(peb, wtr, rbB, nullptr, nullptr, nullptr, nullptr,
                                             2 * S_ - 1, D_, D_);
  gemm_bt<F_DUAL><<<dim3(6, 48), 256, 0, stream>>>(xb, wtq, quB, qvB, ubc, vbc, nullptr,
                                                   B_ * S_, D_, D_);
  gemm_bt<0><<<dim3(6, 48), 256, 0, stream>>>(xb, wtk, kbB, nullptr, nullptr, nullptr, nullptr,
                                              B_ * S_, D_, D_);
  gemm_bt<F_VT><<<dim3(6, 48), 256, 0, stream>>>(xb, wtv, vtB, nullptr, nullptr, nullptr, nullptr,
                                                 B_ * S_, D_, D_);
  // --- attention -> d_out scratch ---
  attn_kernel<<<dim3(S_ / 16, B_ * H_), 256, 0, stream>>>(quB, qvB, kbB, vtB, rbB, atB);
  // --- output projection + residual (in-place into xb) ---
  gemm_bt<F_RES><<<dim3(6, 48), 256, 0, stream>>>(atB, wto, y1B, nullptr, nullptr, nullptr, xb,
                                                  B_ * S_, D_, D_);
  ln_kernel<<<B_ * S_ / 4, 256, 0, stream>>>(y1B, g1c, be1c, x1B, flag, 0);
  // --- FFN ---
  gemm_bt<F_BIAS | F_RELU><<<dim3(24, 48), 256, 0, stream>>>(x1B, wt1, ffB, nullptr, b1c, nullptr,
                                                             nullptr, B_ * S_, FF_, D_);
  gemm_bt<F_BIAS | F_RES><<<dim3(6, 48), 256, 0, stream>>>(ffB, wt2, y2B, nullptr, b2c, nullptr,
                                                           x1B, B_ * S_, D_, FF_);
  ln_kernel<<<B_ * S_ / 4, 256, 0, stream>>>(y2B, g2c, be2c, d_out, flag, 1);
}